// Round 7
// baseline (42.834 us; speedup 1.0000x reference)
//
#include <hip/hip_runtime.h>
#include <hip/hip_bf16.h>

#define HW 3136     // 56*56
#define CC 256
#define MM 72       // K*K*G (real)
#define HH 56
#define WW 56

typedef __attribute__((ext_vector_type(8))) short short8;   // 8 bf16 (4 VGPR)
typedef __attribute__((ext_vector_type(4))) float f32x4;    // MFMA acc / float4

#define WAITVM(n) asm volatile("s_waitcnt vmcnt(" #n ")" ::: "memory")

__device__ __forceinline__ void blockbar() {
    asm volatile("" ::: "memory");        // compiler fence: nothing crosses
    __builtin_amdgcn_s_barrier();         // raw barrier: NO auto vmcnt(0) drain
    asm volatile("" ::: "memory");
}

__device__ inline unsigned short f2b(float f) {
    unsigned u; __builtin_memcpy(&u, &f, 4);
    unsigned r = u + 0x7fffu + ((u >> 16) & 1u);   // RNE to bf16
    return (unsigned short)(r >> 16);
}
__device__ inline float b2f(unsigned short s) {
    unsigned u = ((unsigned)s) << 16; float f; __builtin_memcpy(&f, &u, 4);
    return f;
}
__device__ __forceinline__ unsigned short f2b_native(float f) {
    __hip_bfloat16 h = __float2bfloat16(f);
    unsigned short s; __builtin_memcpy(&s, &h, 2);
    return s;
}

// fire-and-forget 16B global -> LDS DMA (counted in vmcnt; LDS dst MUST be
// wave-uniform base + lane*16 -> all dst index maps below are linear in t)
__device__ __forceinline__ void gl2lds16(const float* g, float* l) {
    __builtin_amdgcn_global_load_lds(
        (const __attribute__((address_space(1))) void*)g,
        (__attribute__((address_space(3))) void*)l, 16, 0, 0);
}

// ---------------------------------------------------------------------------
// k0: fold the two 1x1 convs into bf16 W [80][256] (rows 72..95 zero) and
// fp32 bias [80]. (verified, unchanged)
// ---------------------------------------------------------------------------
__global__ __launch_bounds__(256) void k0_combine(
    const float* __restrict__ w_reduce,   // [128][256]
    const float* __restrict__ b_reduce,   // [128]
    const float* __restrict__ w_span,     // [72][128]
    const float* __restrict__ b_span,     // [72]
    unsigned short* __restrict__ wbf,     // [80][256] bf16
    float* __restrict__ bcomb)            // [80]
{
    __shared__ float red[4][64];
    __shared__ float redb[256];

    const int m  = blockIdx.x;       // 0..79
    const int cq = blockIdx.y;       // 0..3
    const int t  = threadIdx.x;
    const int oq = t >> 6;           // o-chunk (wave id)
    const int cl = t & 63;
    const int c  = cq * 64 + cl;

    float acc = 0.f;
    if (m < MM) {
        const float* wsB = w_span   + m * 128 + oq * 32;
        const float* wrB = w_reduce + (size_t)(oq * 32) * 256 + c;
#pragma unroll 8
        for (int o = 0; o < 32; ++o)
            acc = fmaf(wsB[o], wrB[(size_t)o * 256], acc);
    }
    if (oq != 0) red[oq][cl] = acc;
    __syncthreads();
    if (oq == 0)
        wbf[m * 256 + c] = f2b(acc + red[1][cl] + red[2][cl] + red[3][cl]);

    if (cq == 0) {   // uniform per block -> safe to sync inside
        redb[t] = (m < MM && t < 128) ? w_span[m * 128 + t] * b_reduce[t] : 0.f;
        __syncthreads();
#pragma unroll
        for (int s2 = 128; s2 > 0; s2 >>= 1) {
            if (t < s2) redb[t] += redb[t + s2];
            __syncthreads();
        }
        if (t == 0) bcomb[m] = (m < MM ? b_span[m] : 0.f) + redb[0];
    }
}

// ---------------------------------------------------------------------------
// kA: pipelined MFMA GEMM (r6-verified A-section verbatim). ker written to
// workspace kerb2 as per-tile CONTIGUOUS [72][112] bf16 blocks (16128 B/tile)
// so kB can DMA its half with linear 16B quads.
// Ledger (stage = 3 VM ops t<320 / 2 else; prologue s0,s1):
//   p=0..6 : N = 3 / 2  (stage(p+1) in flight)
//   p==7   : N = 0      (one-time tail drain; epilogue stores follow)
// grid(448 = 8*56 XCD swizzle), block(448). LDS 58368 B -> 2 blk/CU.
// ---------------------------------------------------------------------------
__global__ __launch_bounds__(448, 4) void kA_gemm(
    const float* __restrict__ x,              // [16][256][3136] fp32
    const unsigned short* __restrict__ wbf,   // [80][256] bf16
    const float* __restrict__ bcomb,          // [80]
    unsigned short* __restrict__ kerb2)       // [448 tiles][72][112] bf16
{
    __shared__ __align__(16) float xsb[3 * 3584];           // 43008 B ring
    __shared__ __align__(16) unsigned short wsl[3][2560];   // 15360 B W ring

    const int L   = blockIdx.x;               // 0..447
    const int wk  = (L & 7) * 56 + (L >> 3);  // bijective (448 = 8*56)
    const int b   = wk / 28;
    const int rem = wk - b * 28;
    const int ht  = rem >> 1;                 // 0..13
    const int cs  = rem & 1;                  // column half
    const int h0  = ht * 4;
    const int c0  = cs * 28;
    const int tile = b * 28 + ht * 2 + cs;

    const int t    = threadIdx.x;             // 0..447
    const int lane = t & 63;
    const int wv   = t >> 6;                  // wave 0..6 = GEMM n-tile
    const int l15  = lane & 15;
    const int q    = lane >> 4;

    const int chh   = t / 28;                 // 0..15 (staging decomposition)
    const int rem28 = t - chh * 28;
    const int rA    = rem28 / 7;
    const int qA    = rem28 - rA * 7;

    const float* xb = x + (size_t)b * CC * HW;

    // ---- per-thread constants (identical to verified r2/r4/r6) ----
    const int nb   = wv * 16 + l15;                // GEMM n = tile px
    const int nb2  = q * 112 + nb;                 // B-frag base (j stride 448)
    const int swA  = (l15 ^ (l15 >> 2)) & 3;       // A-frag XOR swizzle
    const int aBo  = l15 * 32 + (q ^ swA) * 8;     // A-frag base (mt stride 512)
    const int cA   = ((chh & 3) << 3) | (chh >> 2);// x-DMA channel perm
    const int pxo  = (h0 + rA) * WW + c0 + qA * 4; // x-DMA pixel offset
    const int wswr = ((t >> 2) ^ (t >> 4)) & 3;    // wbf pre-swizzled source
    const unsigned short* wsrc0 = wbf + (t >> 2) * 256 + ((t & 3) ^ wswr) * 8;

    auto stageX = [&](int s) {                // 2 DMA (rows chh, chh+16)
        const float* sp = xb + (size_t)(s * 32 + cA) * HW + pxo;
        float* dp = xsb + (s % 3) * 3584 + t * 4;
        gl2lds16(sp, dp);
        gl2lds16(sp + (size_t)4 * HW, dp + 1792);
    };
    auto stageW = [&](int s) {                // 1 DMA, waves 0-4 only
        if (t < 320)
            gl2lds16((const float*)(wsrc0 + s * 32), (float*)(wsl[s % 3]) + t * 4);
    };

    f32x4 acc[5];
#pragma unroll
    for (int mt = 0; mt < 5; ++mt)
#pragma unroll
        for (int r = 0; r < 4; ++r)
            acc[mt][r] = bcomb[mt * 16 + q * 4 + r];

    stageX(0); stageW(0);
    stageX(1); stageW(1);

#pragma unroll 1
    for (int p = 0; p < 8; ++p) {
        if (p < 7) { if (t < 320) WAITVM(3); else WAITVM(2); }
        else       { WAITVM(0); }
        blockbar();
        if (p < 6) { stageX(p + 2); stageW(p + 2); }

        const float* bufA = xsb + (p % 3) * 3584;
        const unsigned short* wp = wsl[p % 3];
        union { short8 v; unsigned short u16[8]; } bq;
#pragma unroll
        for (int j = 0; j < 8; ++j)       // row j*4+q holds channel q*8+j
            bq.u16[j] = f2b_native(bufA[nb2 + j * 448]);
#pragma unroll
        for (int mt = 0; mt < 5; ++mt) {
            const short8 aq = *(const short8*)&wp[mt * 512 + aBo];
            acc[mt] = __builtin_amdgcn_mfma_f32_16x16x32_bf16(aq, bq.v, acc[mt], 0, 0, 0);
        }
    }

    // epilogue: store ker tile (rows 72..79 dropped)
    unsigned short* kt = kerb2 + (size_t)tile * 8064;   // 72*112 shorts
#pragma unroll
    for (int mt = 0; mt < 5; ++mt)
#pragma unroll
        for (int r = 0; r < 4; ++r) {
            const int m = mt * 16 + q * 4 + r;
            if (m < MM) kt[m * 112 + nb] = f2b(acc[mt][r]);
        }
}

// ---------------------------------------------------------------------------
// kB: apply. One block = one 128-channel half (hv) of a tile -> 8 phases of
// 16-ch chunks. Single-barrier ring-2: { WAITVM(N); bar; stageB(p+1);
// compute(p) }. N=0 at p==0 (drains ker-DMA + s0 once), else N=1 (leaves
// the previous phase's store in flight; stage(p) is complete). x is
// L3-resident (kA just streamed it) so depth-1 prefetch suffices; the win
// is occupancy: LDS 36736 B -> 4 blk/CU, grid 896 all-resident
// (~24.5 waves/CU vs 14 in the fused kernel). Compute body, DMA maps,
// masks, FP order identical to r6's B phase -> bit-identical output.
// grid(896 = 8*112 XCD swizzle), block(448).
// ---------------------------------------------------------------------------
__global__ __launch_bounds__(448, 7) void kB_apply(
    const float* __restrict__ x,              // [16][256][3136] fp32
    const unsigned short* __restrict__ kerb2, // [448 tiles][72][112] bf16
    float* __restrict__ out)                  // [16][256][3136] fp32
{
    __shared__ __align__(16) float xsb[2 * 3584];           // 28672 B ring
    __shared__ __align__(16) unsigned short klb[36 * 112];  // 8064 B ker half

    const int L   = blockIdx.x;                // 0..895
    const int wk  = (L & 7) * 112 + (L >> 3);  // bijective (896 = 8*112)
    const int b   = wk / 56;
    int r2d = wk - b * 56;
    const int ht  = r2d >> 2;                  // 0..13
    const int cs  = (r2d >> 1) & 1;
    const int hv  = r2d & 1;                   // channel half (128 ch)
    const int h0  = ht * 4;
    const int c0  = cs * 28;
    const int tile = b * 28 + ht * 2 + cs;

    const int t    = threadIdx.x;              // 0..447
    const int chh   = t / 28;                  // 0..15 channel in chunk
    const int rem28 = t - chh * 28;
    const int rA    = rem28 / 7;               // out row in band
    const int qA    = rem28 - rA * 7;          // 4-col strip

    const float* xb = x + (size_t)b * CC * HW;

    // ---- staging source offsets (chunk-invariant, r6 verbatim) ----
    int boff[2];
#pragma unroll
    for (int i = 0; i < 2; ++i) {
        const int f  = i * 448 + t;
        const int fc = f < 864 ? f : 863;      // tail lanes: clamped-dup source
        const int d  = fc / 54;                // ch in chunk 0..15
        const int r2 = fc - d * 54;
        const int rr = r2 / 9;                 // stage row 0..5 (h0-1..h0+4)
        const int qd = r2 - rr * 9;            // quad 0..8
        const int hh = h0 - 1 + rr;
        const int hc = hh < 0 ? 0 : (hh > 55 ? 55 : hh);
        int colc = c0 - 4 + qd * 4;            // 16B-aligned; borders masked
        colc = colc < 0 ? 0 : (colc > 52 ? 52 : colc);
        boff[i] = d * HW + hc * WW + colc;
    }

    // ---- apply masks (r6 verbatim) ----
    float vmm[3];
#pragma unroll
    for (int kh = 0; kh < 3; ++kh) {
        const int row = h0 + rA - 1 + kh;
        vmm[kh] = (row >= 0 && row < HH) ? 1.f : 0.f;
    }
    const float lm  = (cs == 0 && qA == 0) ? 0.f : 1.f;   // w-1 < 0
    const float rmm = (cs == 1 && qA == 6) ? 0.f : 1.f;   // w+4 > 55

    auto stageB = [&](int c) {                 // 2 DMA (16-ch halo chunk)
        const float* gp = xb + (size_t)(hv * 128 + c * 16) * HW;
        float* dp = xsb + (c & 1) * 3584;
        gl2lds16(gp + boff[0], dp + t * 4);
        gl2lds16(gp + boff[1], dp + (448 + t) * 4);
    };

    // ---- prologue: ker half (504 quads) + first chunk ----
    const float* ksf = (const float*)(kerb2 + (size_t)tile * 8064 + hv * 4032);
    float* kld = (float*)klb;
    gl2lds16(ksf + t * 4, kld + t * 4);
    if (t < 56) gl2lds16(ksf + (448 + t) * 4, kld + (448 + t) * 4);
    stageB(0);

    f32x4 kr[9];
#pragma unroll 1
    for (int p = 0; p < 8; ++p) {
        if (p == 0) WAITVM(0);    // one-time: ker + s0 landed
        else        WAITVM(1);    // stage(p) done; store(p-1) stays in flight
        blockbar();
        if (p < 7) stageB(p + 1); // into slot read by compute(p-1): freed by bar

        if ((p & 1) == 0) {       // taps shared by both chunk halves of a group
            const int gl = p >> 1;            // local group 0..3
            ushort4 krb[9];
#pragma unroll
            for (int kk = 0; kk < 9; ++kk)
                krb[kk] = *(const ushort4*)&klb[(gl * 9 + kk) * 112 + rA * 28 + qA * 4];
#pragma unroll
            for (int kh = 0; kh < 3; ++kh) {
#pragma unroll
                for (int j = 0; j < 3; ++j) {
                    const int kk = kh * 3 + j;
                    kr[kk].x = b2f(krb[kk].x) * vmm[kh];
                    kr[kk].y = b2f(krb[kk].y) * vmm[kh];
                    kr[kk].z = b2f(krb[kk].z) * vmm[kh];
                    kr[kk].w = b2f(krb[kk].w) * vmm[kh];
                }
                kr[kh * 3 + 0].x *= lm;       // tap reads col c0+4qA-1
                kr[kh * 3 + 2].w *= rmm;      // tap reads col c0+4qA+4
            }
        }

        const float* bp = xsb + (p & 1) * 3584 + chh * 216;
        f32x4 a = {0.f, 0.f, 0.f, 0.f};
#pragma unroll
        for (int kh = 0; kh < 3; ++kh) {
            const float* rowp = bp + (rA + kh) * 36;
            const f32x4 q0v = *(const f32x4*)(rowp + qA * 4);      // .w = w0-1
            const f32x4 q1v = *(const f32x4*)(rowp + qA * 4 + 4);  // w0..w0+3
            const float tl  = rowp[qA * 4 + 8];                    // w0+4
            const float w0 = q0v.w, w1 = q1v.x, w2 = q1v.y,
                        w3 = q1v.z, w4 = q1v.w, w5 = tl;
            const f32x4 k0v = kr[kh * 3 + 0];
            const f32x4 k1v = kr[kh * 3 + 1];
            const f32x4 k2v = kr[kh * 3 + 2];
            a.x = fmaf(k0v.x, w0, a.x); a.y = fmaf(k0v.y, w1, a.y);
            a.z = fmaf(k0v.z, w2, a.z); a.w = fmaf(k0v.w, w3, a.w);
            a.x = fmaf(k1v.x, w1, a.x); a.y = fmaf(k1v.y, w2, a.y);
            a.z = fmaf(k1v.z, w3, a.z); a.w = fmaf(k1v.w, w4, a.w);
            a.x = fmaf(k2v.x, w2, a.x); a.y = fmaf(k2v.y, w3, a.y);
            a.z = fmaf(k2v.z, w4, a.z); a.w = fmaf(k2v.w, w5, a.w);
        }
        float* ob = out + ((size_t)b * CC + hv * 128 + p * 16 + chh) * HW
                  + (h0 + rA) * WW + c0 + qA * 4;
        *(f32x4*)ob = a;                  // 1 store per thread per phase
    }
}

// ---------------------------------------------------------------------------
extern "C" void kernel_launch(void* const* d_in, const int* in_sizes, int n_in,
                              void* d_out, int out_size, void* d_ws, size_t ws_size,
                              hipStream_t stream) {
    const float* x        = (const float*)d_in[0];
    const float* w_reduce = (const float*)d_in[1];
    const float* b_reduce = (const float*)d_in[2];
    const float* w_span   = (const float*)d_in[3];
    const float* b_span   = (const float*)d_in[4];
    float* out = (float*)d_out;

    char* ws = (char*)d_ws;
    unsigned short* wbf   = (unsigned short*)ws;              // 40960 B
    float*          bcomb = (float*)(ws + 40960);             // 320 B
    unsigned short* kerb2 = (unsigned short*)(ws + 41472);    // 448*16128 B

    k0_combine<<<dim3(80, 4), 256, 0, stream>>>(w_reduce, b_reduce, w_span, b_span,
                                                wbf, bcomb);
    kA_gemm<<<dim3(448), 448, 0, stream>>>(x, wbf, bcomb, kerb2);
    kB_apply<<<dim3(896), 448, 0, stream>>>(x, kerb2, out);
}

// Round 8
// 38.806 us; speedup vs baseline: 1.1038x; 1.1038x over previous
//
#include <hip/hip_runtime.h>
#include <hip/hip_bf16.h>

#define HW 3136     // 56*56
#define CC 256
#define MM 72       // K*K*G (real)
#define HH 56
#define WW 56

typedef __attribute__((ext_vector_type(8))) short short8;   // 8 bf16 (4 VGPR)
typedef __attribute__((ext_vector_type(4))) float f32x4;    // MFMA acc / float4

#define WAITVM(n) asm volatile("s_waitcnt vmcnt(" #n ")" ::: "memory")

__device__ __forceinline__ void blockbar() {
    asm volatile("" ::: "memory");        // compiler fence: nothing crosses
    __builtin_amdgcn_s_barrier();         // raw barrier: NO auto vmcnt(0) drain
    asm volatile("" ::: "memory");
}

__device__ inline unsigned short f2b(float f) {
    unsigned u; __builtin_memcpy(&u, &f, 4);
    unsigned r = u + 0x7fffu + ((u >> 16) & 1u);   // RNE to bf16
    return (unsigned short)(r >> 16);
}
__device__ inline float b2f(unsigned short s) {
    unsigned u = ((unsigned)s) << 16; float f; __builtin_memcpy(&f, &u, 4);
    return f;
}
__device__ __forceinline__ unsigned short f2b_native(float f) {
    __hip_bfloat16 h = __float2bfloat16(f);
    unsigned short s; __builtin_memcpy(&s, &h, 2);
    return s;
}

// fire-and-forget global -> LDS DMA (counted in vmcnt; LDS dst is
// wave-uniform base + lane*size -> dst maps below are linear in t per wave)
__device__ __forceinline__ void gl2lds16(const float* g, float* l) {
    __builtin_amdgcn_global_load_lds(
        (const __attribute__((address_space(1))) void*)g,
        (__attribute__((address_space(3))) void*)l, 16, 0, 0);
}
__device__ __forceinline__ void gl2lds4(const float* g, float* l) {
    __builtin_amdgcn_global_load_lds(
        (const __attribute__((address_space(1))) void*)g,
        (__attribute__((address_space(3))) void*)l, 4, 0, 0);
}

// ---------------------------------------------------------------------------
// k0: fold the two 1x1 convs into bf16 W [80][256] (rows 72..95 zero) and
// fp32 bias [80]. (verified, unchanged)
// ---------------------------------------------------------------------------
__global__ __launch_bounds__(256) void k0_combine(
    const float* __restrict__ w_reduce,   // [128][256]
    const float* __restrict__ b_reduce,   // [128]
    const float* __restrict__ w_span,     // [72][128]
    const float* __restrict__ b_span,     // [72]
    unsigned short* __restrict__ wbf,     // [80][256] bf16
    float* __restrict__ bcomb)            // [80]
{
    __shared__ float red[4][64];
    __shared__ float redb[256];

    const int m  = blockIdx.x;       // 0..79
    const int cq = blockIdx.y;       // 0..3
    const int t  = threadIdx.x;
    const int oq = t >> 6;           // o-chunk (wave id)
    const int cl = t & 63;
    const int c  = cq * 64 + cl;

    float acc = 0.f;
    if (m < MM) {
        const float* wsB = w_span   + m * 128 + oq * 32;
        const float* wrB = w_reduce + (size_t)(oq * 32) * 256 + c;
#pragma unroll 8
        for (int o = 0; o < 32; ++o)
            acc = fmaf(wsB[o], wrB[(size_t)o * 256], acc);
    }
    if (oq != 0) red[oq][cl] = acc;
    __syncthreads();
    if (oq == 0)
        wbf[m * 256 + c] = f2b(acc + red[1][cl] + red[2][cl] + red[3][cl]);

    if (cq == 0) {   // uniform per block -> safe to sync inside
        redb[t] = (m < MM && t < 128) ? w_span[m * 128 + t] * b_reduce[t] : 0.f;
        __syncthreads();
#pragma unroll
        for (int s2 = 128; s2 > 0; s2 >>= 1) {
            if (t < s2) redb[t] += redb[t + s2];
            __syncthreads();
        }
        if (t == 0) bcomb[m] = (m < MM ? b_span[m] : 0.f) + redb[0];
    }
}

// ---------------------------------------------------------------------------
// k_fused (single-barrier ring-3, r6-verified schedule; B-restage DIET):
// 24 phases = 8 GEMM stages (32 ch) + 16 apply chunks (16 ch). One barrier
// per phase: { WAITVM(N); bar; stage(p+2); compute(p); }.
//
// B-stage slimmed from 9 quads/row (36 cols) to 7 aligned core quads
// (28 cols) + 2 edge columns staged as 4-byte DMAs:
//   core : 672 quads  = [ch][6 rows][7 quads], dst floats [0, 2688)
//   edges: 192 scalars = [ch][6 rows][L,R],    dst floats [2688, 2880)
// Slot 11520 B (was 14336) -> B-restage 99 -> 79.6 MB fabric traffic.
// Per-wave stage op count stays 2 (waves 0-3: 2 core; waves 4-6: core+edge)
// so the r6 ledger applies VERBATIM:
//   A p=0..6 : N = 3 (t<320) / 2     A p==7: N = 2 (B0 in flight)
//   B g2==0  : N = 2;  g2=1..14: N = 3;  g2==15: N = 1
// Read side: w1..w4 one aligned f32x4; w0/w5 scalars (interior) or edge
// array (qA==0/6). Post-mask values identical -> bit-identical output.
// grid(448 = 8*56 XCD swizzle), block(448). LDS 74496 B -> 2 blk/CU.
// ---------------------------------------------------------------------------
__global__ __launch_bounds__(448, 4) void k_fused(
    const float* __restrict__ x,              // [16][256][3136] fp32
    const unsigned short* __restrict__ wbf,   // [80][256] bf16
    const float* __restrict__ bcomb,          // [80]
    float* __restrict__ out)                  // [16][256][3136] fp32
{
    __shared__ __align__(16) float xsb[3 * 3584];           // 43008 B ring
    __shared__ __align__(16) unsigned short wsl[3][2560];   // 15360 B W ring
    __shared__ __align__(16) unsigned short kl[MM * 112];   // 16128 B ker bf16

    const int L   = blockIdx.x;               // 0..447
    const int wk  = (L & 7) * 56 + (L >> 3);  // bijective (448 = 8*56)
    const int b   = wk / 28;
    const int rem = wk - b * 28;
    const int ht  = rem >> 1;                 // 0..13
    const int cs  = rem & 1;                  // column half
    const int h0  = ht * 4;
    const int c0  = cs * 28;

    const int t    = threadIdx.x;             // 0..447
    const int lane = t & 63;
    const int wv   = t >> 6;                  // wave 0..6 = GEMM n-tile
    const int l15  = lane & 15;
    const int q    = lane >> 4;

    const int chh   = t / 28;                 // 0..15  (B: channel in chunk)
    const int rem28 = t - chh * 28;
    const int rA    = rem28 / 7;              // out row in band
    const int qA    = rem28 - rA * 7;         // 4-col strip

    const float* xb = x + (size_t)b * CC * HW;

    // ---- A-phase per-thread constants (identical to verified r2/r4/r6) ----
    const int nb   = wv * 16 + l15;                // GEMM n = tile px
    const int nb2  = q * 112 + nb;                 // B-frag base (j stride 448)
    const int swA  = (l15 ^ (l15 >> 2)) & 3;       // A-frag XOR swizzle
    const int aBo  = l15 * 32 + (q ^ swA) * 8;     // A-frag base (mt stride 512)
    const int cA   = ((chh & 3) << 3) | (chh >> 2);// x-DMA channel perm
    const int pxo  = (h0 + rA) * WW + c0 + qA * 4; // x-DMA pixel offset
    const int wswr = ((t >> 2) ^ (t >> 4)) & 3;    // wbf pre-swizzled source
    const unsigned short* wsrc0 = wbf + (t >> 2) * 256 + ((t & 3) ^ wswr) * 8;

    // ---- B-phase staging source offsets (chunk-invariant) ----
    int bcore0, bcore1 = 0, bedge = 0;
    {
        auto coreOff = [&](int f) {           // f -> (ch, stage row, quad)
            const int d  = f / 42;            // 42 = 6 rows * 7 quads
            const int r2 = f - d * 42;
            const int r  = r2 / 7;            // stage row 0..5 (h0-1..h0+4)
            const int qd = r2 - r * 7;        // core quad 0..6 (cols c0..c0+27)
            const int hh = h0 - 1 + r;
            const int hc = hh < 0 ? 0 : (hh > 55 ? 55 : hh);
            return d * HW + hc * WW + c0 + qd * 4;
        };
        bcore0 = coreOff(t);
        if (t < 224) bcore1 = coreOff(448 + t);
        if (t >= 256) {                       // edge scalars e = t-256
            const int e  = t - 256;
            const int d  = e / 12;
            const int r2 = e - d * 12;
            const int r  = r2 >> 1;
            const int sd = r2 & 1;            // 0 = left (c0-1), 1 = right (c0+28)
            const int hh = h0 - 1 + r;
            const int hc = hh < 0 ? 0 : (hh > 55 ? 55 : hh);
            int col = sd ? c0 + 28 : c0 - 1;  // clamped; masked taps ignore value
            col = col < 0 ? 0 : (col > 55 ? 55 : col);
            bedge = d * HW + hc * WW + col;
        }
    }

    // ---- apply masks (chunk-invariant) ----
    float vmm[3];
#pragma unroll
    for (int kh = 0; kh < 3; ++kh) {
        const int row = h0 + rA - 1 + kh;
        vmm[kh] = (row >= 0 && row < HH) ? 1.f : 0.f;
    }
    const float lm  = (cs == 0 && qA == 0) ? 0.f : 1.f;   // w-1 < 0
    const float rmm = (cs == 1 && qA == 6) ? 0.f : 1.f;   // w+4 > 55

    // ---- stage helpers (LDS dst linear in t per wave; slot = phase%3) ----
    auto stageX = [&](int s) {                // 2 DMA (rows chh, chh+16)
        const float* sp = xb + (size_t)(s * 32 + cA) * HW + pxo;
        float* dp = xsb + (s % 3) * 3584 + t * 4;
        gl2lds16(sp, dp);
        gl2lds16(sp + (size_t)4 * HW, dp + 1792);
    };
    auto stageW = [&](int s) {                // 1 DMA, waves 0-4 only
        if (t < 320)
            gl2lds16((const float*)(wsrc0 + s * 32), (float*)(wsl[s % 3]) + t * 4);
    };
    auto stageB = [&](int c) {                // 2 VM ops per wave, all waves
        const float* gp = xb + (size_t)(c * 16) * HW;
        float* dp = xsb + ((8 + c) % 3) * 3584;
        gl2lds16(gp + bcore0, dp + t * 4);                        // waves 0-6
        if (t < 224) gl2lds16(gp + bcore1, dp + (448 + t) * 4);   // waves 0-3
        if (t >= 256) gl2lds4(gp + bedge, dp + 2688 + (t - 256)); // waves 4-6
    };

    // ---- acc init (plain loads; older than all DMA -> drained by 1st wait)
    f32x4 acc[5];
#pragma unroll
    for (int mt = 0; mt < 5; ++mt)
#pragma unroll
        for (int r = 0; r < 4; ++r)
            acc[mt][r] = bcomb[mt * 16 + q * 4 + r];

    // ---- prologue: 2 stages in flight ----
    stageX(0); stageW(0);
    stageX(1); stageW(1);

    // ---------------- A section: 8 GEMM phases, 1 barrier each ----------------
#pragma unroll 1
    for (int p = 0; p < 8; ++p) {
        if (p < 7) { if (t < 320) WAITVM(3); else WAITVM(2); }
        else       { WAITVM(2); }
        blockbar();
        // stage(p+2) into the slot freed by compute(p-1)
        if (p < 6)       { stageX(p + 2); stageW(p + 2); }
        else if (p == 6) { stageB(0); }    // phase 8
        else             { stageB(1); }    // phase 9

        const float* bufA = xsb + (p % 3) * 3584;
        const unsigned short* wp = wsl[p % 3];
        union { short8 v; unsigned short u16[8]; } bq;
#pragma unroll
        for (int j = 0; j < 8; ++j)       // row j*4+q holds channel q*8+j
            bq.u16[j] = f2b_native(bufA[nb2 + j * 448]);
#pragma unroll
        for (int mt = 0; mt < 5; ++mt) {
            const short8 aq = *(const short8*)&wp[mt * 512 + aBo];
            acc[mt] = __builtin_amdgcn_mfma_f32_16x16x32_bf16(aq, bq.v, acc[mt], 0, 0, 0);
        }
        if (p == 7) {                     // ker -> LDS bf16 (rows 72..79 dropped)
#pragma unroll
            for (int mt = 0; mt < 5; ++mt)
#pragma unroll
                for (int r = 0; r < 4; ++r) {
                    const int m = mt * 16 + q * 4 + r;
                    if (m < MM) kl[m * 112 + nb] = f2b(acc[mt][r]);
                }
            asm volatile("s_waitcnt lgkmcnt(0)" ::: "memory");
        }
    }

    // ---------------- B section: 16 apply phases, 1 barrier each --------------
    f32x4 kr[9];
#pragma unroll 1
    for (int g2 = 0; g2 < 16; ++g2) {
        if (g2 == 0)       WAITVM(2);
        else if (g2 <= 14) WAITVM(3);
        else               WAITVM(1);
        blockbar();
        if (g2 <= 13) stageB(g2 + 2);     // into slot freed by compute(g2-1)

        if ((g2 & 1) == 0) {              // taps shared by both chunk halves
            const int g = g2 >> 1;
            ushort4 krb[9];
#pragma unroll
            for (int kk = 0; kk < 9; ++kk)
                krb[kk] = *(const ushort4*)&kl[(g * 9 + kk) * 112 + rA * 28 + qA * 4];
#pragma unroll
            for (int kh = 0; kh < 3; ++kh) {
#pragma unroll
                for (int j = 0; j < 3; ++j) {
                    const int kk = kh * 3 + j;
                    kr[kk].x = b2f(krb[kk].x) * vmm[kh];
                    kr[kk].y = b2f(krb[kk].y) * vmm[kh];
                    kr[kk].z = b2f(krb[kk].z) * vmm[kh];
                    kr[kk].w = b2f(krb[kk].w) * vmm[kh];
                }
                kr[kh * 3 + 0].x *= lm;   // tap reads col c0+4qA-1
                kr[kh * 3 + 2].w *= rmm;  // tap reads col c0+4qA+4
            }
        }

        const float* bp = xsb + ((8 + g2) % 3) * 3584;
        const float* cb = bp + chh * 168;            // core: [ch][6][28]
        const float* eb = bp + 2688 + chh * 12;      // edges: [ch][6][2]
        f32x4 a = {0.f, 0.f, 0.f, 0.f};
#pragma unroll
        for (int kh = 0; kh < 3; ++kh) {
            const float* rowp = cb + (rA + kh) * 28;
            const f32x4 q1v = *(const f32x4*)(rowp + qA * 4);           // w1..w4
            const float w0 = (qA > 0) ? rowp[qA * 4 - 1] : eb[(rA + kh) * 2];
            const float w5 = (qA < 6) ? rowp[qA * 4 + 4] : eb[(rA + kh) * 2 + 1];
            const float w1 = q1v.x, w2 = q1v.y, w3 = q1v.z, w4 = q1v.w;
            const f32x4 k0v = kr[kh * 3 + 0];
            const f32x4 k1v = kr[kh * 3 + 1];
            const f32x4 k2v = kr[kh * 3 + 2];
            a.x = fmaf(k0v.x, w0, a.x); a.y = fmaf(k0v.y, w1, a.y);
            a.z = fmaf(k0v.z, w2, a.z); a.w = fmaf(k0v.w, w3, a.w);
            a.x = fmaf(k1v.x, w1, a.x); a.y = fmaf(k1v.y, w2, a.y);
            a.z = fmaf(k1v.z, w3, a.z); a.w = fmaf(k1v.w, w4, a.w);
            a.x = fmaf(k2v.x, w2, a.x); a.y = fmaf(k2v.y, w3, a.y);
            a.z = fmaf(k2v.z, w4, a.z); a.w = fmaf(k2v.w, w5, a.w);
        }
        float* ob = out + ((size_t)b * CC + g2 * 16 + chh) * HW
                  + (h0 + rA) * WW + c0 + qA * 4;
        *(f32x4*)ob = a;                  // 1 store per thread per phase
    }
}

// ---------------------------------------------------------------------------
extern "C" void kernel_launch(void* const* d_in, const int* in_sizes, int n_in,
                              void* d_out, int out_size, void* d_ws, size_t ws_size,
                              hipStream_t stream) {
    const float* x        = (const float*)d_in[0];
    const float* w_reduce = (const float*)d_in[1];
    const float* b_reduce = (const float*)d_in[2];
    const float* w_span   = (const float*)d_in[3];
    const float* b_span   = (const float*)d_in[4];
    float* out = (float*)d_out;

    char* ws = (char*)d_ws;
    unsigned short* wbf   = (unsigned short*)ws;              // 40960 B
    float*          bcomb = (float*)(ws + 40960);             // 320 B

    k0_combine<<<dim3(80, 4), 256, 0, stream>>>(w_reduce, b_reduce, w_span, b_span,
                                                wbf, bcomb);
    k_fused<<<dim3(448), 448, 0, stream>>>(x, wbf, bcomb, out);
}